// Round 1
// baseline (90.631 us; speedup 1.0000x reference)
//
#include <hip/hip_runtime.h>
#include <math.h>

#define Bq 32
#define Nq 1024
#define BPR 16            // blocks per row in pair kernel
#define IPB (Nq / BPR)    // i-values per block = 64
#define TPB 256

// ---------------- zero the per-row accumulators ----------------
__global__ void zero_acc_kernel(float* __restrict__ acc) {
    acc[threadIdx.x] = 0.0f;   // 64 floats = 32 rows x {loss, cnt}
}

// ---------------- per-row discount via mask cumsum ----------------
__global__ __launch_bounds__(1024)
void disc_kernel(const int* __restrict__ masks, float* __restrict__ disc) {
    const int row = blockIdx.x;
    const int t = threadIdx.x;
    const int lane = t & 63;
    const int wid = t >> 6;          // 16 waves

    const int mv = (masks[row * Nq + t] > 0) ? 1 : 0;

    // wave-level inclusive scan
    int val = mv;
#pragma unroll
    for (int off = 1; off < 64; off <<= 1) {
        int n = __shfl_up(val, off, 64);
        if (lane >= off) val += n;
    }

    __shared__ int wsum[16];
    if (lane == 63) wsum[wid] = val;
    __syncthreads();

    // scan the 16 wave totals (inclusive) using lanes 0..15 of wave 0
    if (wid == 0 && lane < 16) {
        int v = wsum[lane];
#pragma unroll
        for (int off = 1; off < 16; off <<= 1) {
            int n = __shfl_up(v, off, 16);
            if (lane >= off) v += n;
        }
        wsum[lane] = v;
    }
    __syncthreads();

    const int cs = val + (wid > 0 ? wsum[wid - 1] : 0);   // 1-indexed count at valid slot
    // disc[k] = 1/log2(k+2); cs = k+1 at valid slots -> 1/log2(cs+1)
    const float d = mv ? (1.0f / log2f((float)cs + 1.0f)) : 0.0f;
    disc[row * Nq + t] = d;
}

// ---------------- pairwise loss ----------------
__global__ __launch_bounds__(TPB)
void pair_kernel(const float* __restrict__ yp,
                 const float* __restrict__ yt,
                 const float* __restrict__ disc,
                 float* __restrict__ acc) {
    const int row = blockIdx.y;
    const int chunk = blockIdx.x;
    const int tid = threadIdx.x;

    __shared__ float sp[Nq];
    __shared__ float st[Nq];
    __shared__ float sd[Nq];
    for (int k = tid; k < Nq; k += TPB) {
        sp[k] = yp[row * Nq + k];
        st[k] = yt[row * Nq + k];
        sd[k] = disc[row * Nq + k];
    }
    __syncthreads();

    float loss = 0.0f;
    float cnt = 0.0f;

    const int i0 = chunk * IPB;
#pragma unroll 1
    for (int i = i0; i < i0 + IPB; ++i) {
        const float di = sd[i];
        if (di <= 0.0f) continue;           // uniform branch: i invalid -> no pairs
        const float pi = sp[i];
        const float ti = st[i];
#pragma unroll
        for (int jj = 0; jj < Nq; jj += TPB) {
            const int j = jj + tid;
            const float dj = sd[j];
            const float td = ti - st[j];
            const bool pos = (td > 0.0f) & (dj > 0.0f);
            if (pos) {
                const float x = sp[j] - pi;          // == -sigma * (pi - pj), sigma = 1
                const float a = __expf(-fabsf(x));
                const float spv = fmaxf(x, 0.0f) + __logf(1.0f + a);  // stable softplus
                loss += spv * (di + dj);
                cnt += 1.0f;
            }
        }
    }

    // block reduction: wave shfl-reduce then LDS across the 4 waves
    const int lane = tid & 63;
    const int wid = tid >> 6;
#pragma unroll
    for (int off = 32; off > 0; off >>= 1) {
        loss += __shfl_down(loss, off, 64);
        cnt  += __shfl_down(cnt, off, 64);
    }
    __shared__ float rl[4], rc[4];
    if (lane == 0) { rl[wid] = loss; rc[wid] = cnt; }
    __syncthreads();
    if (tid == 0) {
        float L = rl[0] + rl[1] + rl[2] + rl[3];
        float C = rc[0] + rc[1] + rc[2] + rc[3];
        atomicAdd(&acc[2 * row + 0], L);
        atomicAdd(&acc[2 * row + 1], C);
    }
}

// ---------------- final reduction over rows ----------------
__global__ void final_kernel(const float* __restrict__ acc, float* __restrict__ out) {
    const int t = threadIdx.x;   // 64 threads
    float v = 0.0f;
    if (t < Bq) {
        const float L = acc[2 * t + 0];
        const float C = acc[2 * t + 1];
        v = L / (C + 1e-12f);
    }
#pragma unroll
    for (int off = 32; off > 0; off >>= 1) v += __shfl_down(v, off, 64);
    if (t == 0) out[0] = v / (float)Bq;
}

extern "C" void kernel_launch(void* const* d_in, const int* in_sizes, int n_in,
                              void* d_out, int out_size, void* d_ws, size_t ws_size,
                              hipStream_t stream) {
    const float* y_pred = (const float*)d_in[0];
    const float* y_true = (const float*)d_in[1];
    const int*   masks  = (const int*)d_in[2];
    float* out = (float*)d_out;

    float* disc = (float*)d_ws;                 // B*N floats = 128 KB
    float* acc  = disc + Bq * Nq;               // 2*B floats

    zero_acc_kernel<<<1, 64, 0, stream>>>(acc);
    disc_kernel<<<Bq, 1024, 0, stream>>>(masks, disc);
    pair_kernel<<<dim3(BPR, Bq), TPB, 0, stream>>>(y_pred, y_true, disc, acc);
    final_kernel<<<1, 64, 0, stream>>>(acc, out);
}

// Round 2
// 81.296 us; speedup vs baseline: 1.1148x; 1.1148x over previous
//
#include <hip/hip_runtime.h>
#include <math.h>

#define Bq 32
#define Nq 1024
#define BPR 16            // blocks per row in pair kernel
#define TPB 256

// ws layout:
//   float4 cw[Bq*Nq]   compacted (p, t, d, 0) per row      512 KB
//   float  acc[2*Bq]   per-row {loss, cnt}
//   int    vcount[Bq]  valid count per row
//   int    done[1]     completed-block counter

// ---------------- prep: scan masks, compact valid items, zero accumulators ----
__global__ __launch_bounds__(1024)
void prep_kernel(const float* __restrict__ yp,
                 const float* __restrict__ yt,
                 const int* __restrict__ masks,
                 float4* __restrict__ cw,
                 float* __restrict__ acc,
                 int* __restrict__ vcount,
                 int* __restrict__ done) {
    const int row = blockIdx.x;
    const int t = threadIdx.x;
    const int lane = t & 63;
    const int wid = t >> 6;          // 16 waves

    const int mv = (masks[row * Nq + t] > 0) ? 1 : 0;

    // wave-level inclusive scan
    int val = mv;
#pragma unroll
    for (int off = 1; off < 64; off <<= 1) {
        int n = __shfl_up(val, off, 64);
        if (lane >= off) val += n;
    }

    __shared__ int wsum[16];
    if (lane == 63) wsum[wid] = val;
    __syncthreads();

    if (wid == 0 && lane < 16) {
        int v = wsum[lane];
#pragma unroll
        for (int off = 1; off < 16; off <<= 1) {
            int n = __shfl_up(v, off, 16);
            if (lane >= off) v += n;
        }
        wsum[lane] = v;
    }
    __syncthreads();

    const int cs = val + (wid > 0 ? wsum[wid - 1] : 0);   // 1-indexed rank among valid
    const int V = wsum[15];

    if (mv) {
        // discount = 1/log2(k+2), k = cs-1  ->  1/log2(cs+1)
        const float d = 1.0f / log2f((float)cs + 1.0f);
        cw[row * Nq + (cs - 1)] = make_float4(yp[row * Nq + t], yt[row * Nq + t], d, 0.0f);
    }
    if (t == 0) {
        vcount[row] = V;
        acc[2 * row + 0] = 0.0f;
        acc[2 * row + 1] = 0.0f;
    }
    if (row == 0 && t == 1) *done = 0;
}

// ---------------- pair loss over compacted triangular pairs + fused final ----
__global__ __launch_bounds__(TPB)
void pair_kernel(const float4* __restrict__ cw,
                 float* __restrict__ acc,
                 const int* __restrict__ vcount,
                 int* __restrict__ done,
                 float* __restrict__ out) {
    const int row = blockIdx.y;
    const int V = vcount[row];

    __shared__ float4 sv[Nq];
    for (int s = threadIdx.x; s < V; s += TPB) sv[s] = cw[row * Nq + s];
    __syncthreads();

    const int P = V * (V - 1) / 2;            // total unordered pairs (<= 523776)
    const int T = BPR * TPB;                  // threads per row
    const int tgl = blockIdx.x * TPB + threadIdx.x;
    const int chunk = (P + T - 1) / T;
    const int k0 = tgl * chunk;
    const int k1 = min(k0 + chunk, P);

    float loss = 0.0f;
    float cnt = 0.0f;

    if (k0 < k1) {
        // pairs enumerated as (i, j) with 0 <= j < i < V; tri(i) = i(i-1)/2
        int i = (int)((1.0 + sqrt(1.0 + 8.0 * (double)k0)) * 0.5);
        if (i < 1) i = 1;
        while (i * (i - 1) / 2 > k0) --i;
        while ((i + 1) * i / 2 <= k0) ++i;
        int j = k0 - i * (i - 1) / 2;

        float4 qi = sv[i];
#pragma unroll 1
        for (int k = k0; k < k1; ++k) {
            const float4 qj = sv[j];
            const bool win = qi.y > qj.y;                 // true_i > true_j ?
            const float x = win ? (qj.x - qi.x) : (qi.x - qj.x);   // pred_loser - pred_winner
            const float a = __expf(-fabsf(x));
            const float spv = fmaxf(x, 0.0f) + __logf(1.0f + a);   // stable softplus
            const bool ok = (qi.y != qj.y);
            const float w = ok ? (qi.z + qj.z) : 0.0f;
            loss = fmaf(spv, w, loss);
            cnt += ok ? 1.0f : 0.0f;
            if (++j == i) { j = 0; ++i; if (i < V) qi = sv[i]; }
        }
    }

    // block reduction
    const int lane = threadIdx.x & 63;
    const int wid = threadIdx.x >> 6;
#pragma unroll
    for (int off = 32; off > 0; off >>= 1) {
        loss += __shfl_down(loss, off, 64);
        cnt  += __shfl_down(cnt, off, 64);
    }
    __shared__ float rl[4], rc[4];
    if (lane == 0) { rl[wid] = loss; rc[wid] = cnt; }
    __syncthreads();

    if (threadIdx.x == 0) {
        const float L = rl[0] + rl[1] + rl[2] + rl[3];
        const float C = rc[0] + rc[1] + rc[2] + rc[3];
        atomicAdd(&acc[2 * row + 0], L);
        atomicAdd(&acc[2 * row + 1], C);
        __threadfence();
        const int old = __hip_atomic_fetch_add(done, 1, __ATOMIC_ACQ_REL, __HIP_MEMORY_SCOPE_AGENT);
        if (old == BPR * Bq - 1) {
            // last block: final reduction over rows
            float s = 0.0f;
            for (int r = 0; r < Bq; ++r) {
                const float L2 = __hip_atomic_load(&acc[2 * r + 0], __ATOMIC_RELAXED, __HIP_MEMORY_SCOPE_AGENT);
                const float C2 = __hip_atomic_load(&acc[2 * r + 1], __ATOMIC_RELAXED, __HIP_MEMORY_SCOPE_AGENT);
                s += L2 / (C2 + 1e-12f);
            }
            out[0] = s / (float)Bq;
        }
    }
}

extern "C" void kernel_launch(void* const* d_in, const int* in_sizes, int n_in,
                              void* d_out, int out_size, void* d_ws, size_t ws_size,
                              hipStream_t stream) {
    const float* y_pred = (const float*)d_in[0];
    const float* y_true = (const float*)d_in[1];
    const int*   masks  = (const int*)d_in[2];
    float* out = (float*)d_out;

    float4* cw    = (float4*)d_ws;
    float*  acc   = (float*)(cw + Bq * Nq);
    int*    vcount= (int*)(acc + 2 * Bq);
    int*    done  = vcount + Bq;

    prep_kernel<<<Bq, 1024, 0, stream>>>(y_pred, y_true, masks, cw, acc, vcount, done);
    pair_kernel<<<dim3(BPR, Bq), TPB, 0, stream>>>(cw, acc, vcount, done, out);
}